// Round 6
// baseline (433.862 us; speedup 1.0000x reference)
//
#include <hip/hip_runtime.h>
#include <hip/hip_bf16.h>

typedef __bf16 bf16;
typedef __attribute__((ext_vector_type(8))) __bf16 bf16x8;
typedef __attribute__((ext_vector_type(4))) __bf16 bf16x4;
typedef __attribute__((ext_vector_type(4))) float  f32x4;

typedef const void __attribute__((address_space(1)))* gas_t;
typedef void __attribute__((address_space(3)))* las_t;

__device__ __forceinline__ void gload16(const void* g, void* l) {
  __builtin_amdgcn_global_load_lds((gas_t)g, (las_t)l, 16, 0, 0);
}
__device__ __forceinline__ f32x4 mfma16(bf16x8 a, bf16x8 b, f32x4 c) {
  return __builtin_amdgcn_mfma_f32_16x16x32_bf16(a, b, c, 0, 0, 0);
}
#define BARRIER() do { asm volatile("" ::: "memory"); \
  __builtin_amdgcn_s_barrier(); asm volatile("" ::: "memory"); } while (0)

constexpr int SEQL = 2048;
constexpr int DM   = 2048;   // model dim
constexpr int HD   = 128;    // head dim
constexpr int MR   = 4096;   // B*S rows

// ---------------- fp32 -> bf16 convert (x) ----------------
__global__ __launch_bounds__(256) void cvt_x(const float* __restrict__ x,
                                             bf16* __restrict__ xb) {
  const size_t i = ((size_t)blockIdx.x * 256 + threadIdx.x) * 4;
  const f32x4 v = *reinterpret_cast<const f32x4*>(x + i);
  bf16x4 o;
  #pragma unroll
  for (int j = 0; j < 4; ++j) o[j] = (bf16)v[j];
  *reinterpret_cast<bf16x4*>(xb + i) = o;
}

// ---------------- weight transpose + convert: [K][N] f32 -> [N][K] bf16 ----------------
__global__ __launch_bounds__(256) void transpose_w(
    const float* __restrict__ w0, const float* __restrict__ w1,
    const float* __restrict__ w2, const float* __restrict__ w3,
    bf16* __restrict__ wqkvt, bf16* __restrict__ wot) {
  const int z = blockIdx.z;
  const float* src = (z == 0) ? w0 : (z == 1) ? w1 : (z == 2) ? w2 : w3;
  bf16* dst = (z < 3) ? (wqkvt + (size_t)z * DM * DM) : wot;
  __shared__ float tile[32][33];
  const int tx = threadIdx.x, ty = threadIdx.y;
  const int x0 = blockIdx.x * 32, y0 = blockIdx.y * 32;
  #pragma unroll
  for (int i = 0; i < 4; ++i)
    tile[ty + 8 * i][tx] = src[(size_t)(y0 + ty + 8 * i) * DM + x0 + tx];
  __syncthreads();
  #pragma unroll
  for (int i = 0; i < 4; ++i)
    dst[(size_t)(x0 + ty + 8 * i) * DM + y0 + tx] = (bf16)tile[tx][ty + 8 * i];
}

// ---------------- RoPE (in-place on Q and K, bf16) ----------------
__global__ __launch_bounds__(256) void rope_k(bf16* __restrict__ Q,
                                              bf16* __restrict__ Kk,
                                              const float* __restrict__ fc,
                                              const float* __restrict__ fs) {
  bf16* X = blockIdx.y ? Kk : Q;
  const size_t tid = (size_t)blockIdx.x * 256 + threadIdx.x;
  const size_t e0 = tid * 8;
  const int col = (int)(e0 & (DM - 1));
  const int row = (int)(e0 >> 11);
  const int s   = row & (SEQL - 1);
  const int p0  = (col & (HD - 1)) >> 1;
  bf16x8 v = *reinterpret_cast<bf16x8*>(X + e0);
  const f32x4 c  = *reinterpret_cast<const f32x4*>(fc + (size_t)s * 64 + p0);
  const f32x4 sn = *reinterpret_cast<const f32x4*>(fs + (size_t)s * 64 + p0);
  #pragma unroll
  for (int j = 0; j < 4; ++j) {
    const float x0 = (float)v[2 * j], x1 = (float)v[2 * j + 1];
    v[2 * j]     = (bf16)(x0 * c[j] - x1 * sn[j]);
    v[2 * j + 1] = (bf16)(x0 * sn[j] + x1 * c[j]);
  }
  *reinterpret_cast<bf16x8*>(X + e0) = v;
}

// ================= 256x256 8-phase bf16 GEMM rev2 =================
// C[M][N] = A[M][K]*Bt[N][K]^T. 512 thr / 8 waves (2M x 4N), BK=64,
// LDS 128 KiB (2dbuf x {A,B} x 2 half). A-frags software-pipelined across
// phases; steady-state vmcnt(4) at ph3 + barrier; XCD swizzle; involutive
// XOR swizzle unit^=(row&7) both sides. F32OUT selects f32 epilogue.
#define LDA4(DST, BASE, ROWOFF)                                                \
  {                                                                            \
    const char* ap_ = (BASE) + ((ROWOFF) + lo) * 128;                          \
    DST[0] = *(const bf16x8*)(ap_ + su0);                                      \
    DST[1] = *(const bf16x8*)(ap_ + su1);                                      \
    DST[2] = *(const bf16x8*)(ap_ + 2048 + su0);                               \
    DST[3] = *(const bf16x8*)(ap_ + 2048 + su1);                               \
  }
#define MFMAQ(Q, AR)                                                           \
  {                                                                            \
    __builtin_amdgcn_s_setprio(1);                                             \
    _Pragma("unroll")                                                          \
    for (int nf = 0; nf < 4; ++nf) {                                           \
      acc[2 * (Q)][nf]     = mfma16(AR[0], bfr[nf][0], acc[2 * (Q)][nf]);      \
      acc[2 * (Q)][nf]     = mfma16(AR[1], bfr[nf][1], acc[2 * (Q)][nf]);      \
      acc[2 * (Q) + 1][nf] = mfma16(AR[2], bfr[nf][0], acc[2 * (Q) + 1][nf]);  \
      acc[2 * (Q) + 1][nf] = mfma16(AR[3], bfr[nf][1], acc[2 * (Q) + 1][nf]);  \
    }                                                                          \
    __builtin_amdgcn_s_setprio(0);                                             \
  }

template <bool F32OUT>
__global__ __launch_bounds__(512, 2) void gemm8(
    const bf16* __restrict__ A, const bf16* __restrict__ Bt,
    void* __restrict__ Cv, const int M, const int N, const int K) {
  __shared__ __attribute__((aligned(16))) char lds[131072];
  const int t = threadIdx.x;
  const int wid = t >> 6, lane = t & 63, lo = lane & 15, hi = lane >> 4;
  const int wm = wid >> 2, wn = wid & 3;

  // XCD-aware swizzle: A-panels L2-resident per XCD
  const int bid = blockIdx.x;
  const int xcd = bid & 7, idx = bid >> 3;
  const int my = (xcd << 1) | (idx & 1);
  const int nxz = idx >> 1;
  const int nx = nxz & 7, z = nxz >> 3;
  const int m0 = my * 256, n0 = nx * 256;
  const bf16* Bt_ = Bt + (size_t)z * N * K;

  const int urow  = (wid << 3) + (lane >> 3);
  const int uunit = (lane & 7) ^ ((lane >> 3) & 7);
  const bf16* gA = A   + (size_t)(m0 + urow) * K + uunit * 8;
  const bf16* gB = Bt_ + (size_t)(n0 + urow) * K + uunit * 8;
  char* lw = lds + wid * 1024;
  const int NT = K >> 6;

  auto stg = [&](const bf16* gbase, int buf, int op, int h, int kt) {
    const bf16* g = gbase + (size_t)(h * 128) * K + kt * 64;
    char* l = lw + (((buf << 1) | op) * 2 + h) * 16384;
    gload16(g, l);
    gload16(g + (size_t)64 * K, l + 8192);
  };
  auto stB0 = [&](int k2) { stg(gB, k2 & 1, 1, 0, k2); };
  auto stB1 = [&](int k2) { stg(gB, k2 & 1, 1, 1, k2); };
  auto stA0 = [&](int k2) { stg(gA, k2 & 1, 0, 0, k2); };
  auto stA1 = [&](int k2) { stg(gA, k2 & 1, 0, 1, k2); };

  f32x4 acc[8][4];
  #pragma unroll
  for (int i = 0; i < 8; ++i)
    #pragma unroll
    for (int j = 0; j < 4; ++j) acc[i][j] = (f32x4){0.f, 0.f, 0.f, 0.f};

  const int su0 = (hi ^ (lo & 7)) * 16;
  const int su1 = ((4 + hi) ^ (lo & 7)) * 16;

  stB0(0); stB1(0); stA0(0); stA1(0);
  stB0(1); stB1(1); stA0(1); stA1(1);
  asm volatile("s_waitcnt vmcnt(8)" ::: "memory");
  BARRIER();

  bf16x8 aP0[4], aP1[4];
  LDA4(aP0, lds + wm * 16384, 0);

  #pragma unroll 1
  for (int kt = 0; kt < NT; ++kt) {
    const int bc = kt & 1;
    const char* aB = lds + (bc * 4 + wm) * 16384;
    const char* bB = lds + ((bc * 2 + 1) * 2 + (wn >> 1)) * 16384;
    const char* aN = lds + (((kt + 1) & 1) * 4 + wm) * 16384;
    bf16x8 bfr[4][2];
    {
      const char* bp = bB + ((wn & 1) * 64 + lo) * 128;
      #pragma unroll
      for (int nf = 0; nf < 4; ++nf) {
        bfr[nf][0] = *(const bf16x8*)(bp + nf * 2048 + su0);
        bfr[nf][1] = *(const bf16x8*)(bp + nf * 2048 + su1);
      }
    }
    LDA4(aP1, aB, 32);
    BARRIER();
    MFMAQ(0, aP0)
    BARRIER();
    LDA4(aP0, aB, 64);
    if (kt + 2 < NT) stB0(kt + 2);
    BARRIER();
    MFMAQ(1, aP1)
    BARRIER();
    LDA4(aP1, aB, 96);
    if (kt + 2 < NT) stB1(kt + 2);
    BARRIER();
    MFMAQ(2, aP0)
    BARRIER();
    if (kt + 2 < NT)      { asm volatile("s_waitcnt vmcnt(4)" ::: "memory"); }
    else if (kt + 1 < NT) { asm volatile("s_waitcnt vmcnt(0)" ::: "memory"); }
    BARRIER();
    if (kt + 1 < NT) LDA4(aP0, aN, 0);
    if (kt + 2 < NT) { stA0(kt + 2); stA1(kt + 2); }
    MFMAQ(3, aP1)
    BARRIER();
  }

  // epilogue: C/D layout col=lane&15, row=(lane>>4)*4+r  [verified m89/m91]
  #pragma unroll
  for (int mf = 0; mf < 8; ++mf)
    #pragma unroll
    for (int nf = 0; nf < 4; ++nf)
      #pragma unroll
      for (int r = 0; r < 4; ++r) {
        const size_t row = m0 + wm * 128 + mf * 16 + hi * 4 + r;
        const size_t col = n0 + wn * 64 + nf * 16 + lo;
        if (F32OUT)
          ((float*)Cv)[((size_t)z * M * N) + row * N + col] = acc[mf][nf][r];
        else
          ((bf16*)Cv)[((size_t)z * M * N) + row * N + col] = (bf16)acc[mf][nf][r];
      }
}

// ---------------- causal flash attention fwd (v4) ----------------
// 256 thr / 4 waves, 32 q-rows per wave (2 Q-sets) -> each K/V fragment
// ds_read feeds 2 MFMAs (halves LDS reads per MFMA). q-tile 128, KVBLK 64.
// Grid (16,16,2); z-complement remap (qi = b ? 15-qx : qx) makes the two
// co-resident blocks per CU sum to uniform 36 KV-tiles; the 2 blocks are
// independent (no shared barriers) -> MFMA/LDS/VALU overlap across blocks.
__global__ __launch_bounds__(256, 2) void flash_fwd(
    const bf16* __restrict__ Qg, const bf16* __restrict__ Kg,
    const bf16* __restrict__ Vg, bf16* __restrict__ Og) {
  const int t = threadIdx.x;
  const int wid = t >> 6, lane = t & 63, lo = lane & 15, hi = lane >> 4;
  const int h  = blockIdx.y;
  const int b  = blockIdx.z;
  const int qi = b ? (15 - (int)blockIdx.x) : (int)blockIdx.x;
  const int q0 = qi * 128;

  __shared__ bf16 Ks[64 * 128];    // [kv][d]  swizzled (16 units/row, key kv&15)
  __shared__ bf16 Vt[128 * 64];    // [d][kv]  swizzled (key (d^(d>>3))&7)
  __shared__ bf16 Ps[4][32 * 64];  // per-wave P [q 32][kv 64], key q&7

  const size_t hoff = (size_t)b * SEQL * DM + (size_t)h * HD;
  const float SCALE_LOG2 = 0.12751743f;   // (1/sqrt(128)) * log2(e)

  const int krow = t >> 4;                 // 0..15
  const int kul  = ((t & 15) ^ krow) * 8;
  const int vd0  = (t & 31) * 4;
  const int vg   = t >> 5;                 // 0..7
  char* myP = (char*)(Ps[wid]);
  const f32x4 zero4 = {0.f, 0.f, 0.f, 0.f};

  // Q B-frags: set s covers q = q0 + wid*32 + s*16 + lo
  bf16x8 qf[2][4];
  #pragma unroll
  for (int s = 0; s < 2; ++s) {
    const bf16* qrow = Qg + hoff + (size_t)(q0 + wid * 32 + s * 16 + lo) * DM;
    #pragma unroll
    for (int kc = 0; kc < 4; ++kc)
      qf[s][kc] = *reinterpret_cast<const bf16x8*>(qrow + kc * 32 + hi * 8);
  }

  f32x4 acc[2][8];
  #pragma unroll
  for (int s = 0; s < 2; ++s)
    #pragma unroll
    for (int i = 0; i < 8; ++i) acc[s][i] = zero4;
  float m_run[2] = {-1e30f, -1e30f}, l_run[2] = {0.f, 0.f};

  const int ntiles = q0 / 64 + 2;
  #pragma unroll 1
  for (int it = 0; it < ntiles; ++it) {
    const int kv0 = it * 64;
    // ---- stage K tile (4 x global_load_lds, pre-swizzled source) ----
    {
      const bf16* gK = Kg + hoff + (size_t)(kv0 + krow) * DM + kul;
      char* lK = (char*)Ks + wid * 1024;
      #pragma unroll
      for (int j = 0; j < 4; ++j)
        gload16(gK + (size_t)j * 16 * DM, lK + j * 4096);
    }
    // ---- stage V^T tile (coalesced 8B loads -> swizzled b128 writes) ----
    {
      const bf16* gV = Vg + hoff + (size_t)kv0 * DM + vd0;
      bf16x4 ld[8];
      #pragma unroll
      for (int e = 0; e < 8; ++e)
        ld[e] = *reinterpret_cast<const bf16x4*>(gV + (size_t)(vg * 8 + e) * DM);
      #pragma unroll
      for (int c = 0; c < 4; ++c) {
        const int d = vd0 + c;
        const int sw = (d ^ (d >> 3)) & 7;
        bf16x8 pk;
        #pragma unroll
        for (int e = 0; e < 8; ++e) pk[e] = ld[e][c];
        *reinterpret_cast<bf16x8*>(Vt + d * 64 + ((vg ^ sw) * 8)) = pk;
      }
    }
    __syncthreads();

    // ---- S^T = K Q^T, both Q-sets share each K fragment ----
    f32x4 sv[2][4];
    #pragma unroll
    for (int s = 0; s < 2; ++s)
      #pragma unroll
      for (int nf = 0; nf < 4; ++nf) sv[s][nf] = zero4;
    #pragma unroll
    for (int nf = 0; nf < 4; ++nf) {
      const bf16* krp = Ks + (nf * 16 + lo) * 128;
      #pragma unroll
      for (int kc = 0; kc < 4; ++kc) {
        const bf16x8 kb = *reinterpret_cast<const bf16x8*>(krp + (((kc * 4 + hi) ^ lo) * 8));
        sv[0][nf] = mfma16(kb, qf[0][kc], sv[0][nf]);
        sv[1][nf] = mfma16(kb, qf[1][kc], sv[1][nf]);
      }
    }
    // ---- per-set: scale + mask + in-lane online softmax + P store ----
    #pragma unroll
    for (int s = 0; s < 2; ++s) {
      const int qrow = q0 + wid * 32 + s * 16 + lo;
      const bool boundary = (kv0 + 63 > q0 + wid * 32 + s * 16);
      #pragma unroll
      for (int nf = 0; nf < 4; ++nf)
        #pragma unroll
        for (int r = 0; r < 4; ++r) {
          float v = sv[s][nf][r] * SCALE_LOG2;
          if (boundary && (kv0 + nf * 16 + hi * 4 + r > qrow)) v = -1e30f;
          sv[s][nf][r] = v;
        }
      float pmax = -1e30f;
      #pragma unroll
      for (int nf = 0; nf < 4; ++nf)
        #pragma unroll
        for (int r = 0; r < 4; ++r) pmax = fmaxf(pmax, sv[s][nf][r]);
      pmax = fmaxf(pmax, __shfl_xor(pmax, 16, 64));
      pmax = fmaxf(pmax, __shfl_xor(pmax, 32, 64));
      float mnew = m_run[s];
      if (!__all(pmax <= m_run[s])) {
        mnew = fmaxf(m_run[s], pmax);
        const float fctr = exp2f(m_run[s] - mnew);
        m_run[s] = mnew;
        l_run[s] *= fctr;
        float fa[4];
        #pragma unroll
        for (int r = 0; r < 4; ++r) fa[r] = __shfl(fctr, hi * 4 + r, 64);
        #pragma unroll
        for (int i = 0; i < 8; ++i)
          #pragma unroll
          for (int r = 0; r < 4; ++r) acc[s][i][r] *= fa[r];
      }
      float sum = 0.f;
      #pragma unroll
      for (int nf = 0; nf < 4; ++nf)
        #pragma unroll
        for (int r = 0; r < 4; ++r) {
          const float p = exp2f(sv[s][nf][r] - mnew);
          sv[s][nf][r] = p;
          sum += p;
        }
      sum += __shfl_xor(sum, 16, 64);
      sum += __shfl_xor(sum, 32, 64);
      l_run[s] += sum;
      // P -> LDS: row q = s*16+lo, 16B-unit swizzle key (lo&7)
      #pragma unroll
      for (int nf = 0; nf < 4; ++nf) {
        bf16x4 w;
        #pragma unroll
        for (int r = 0; r < 4; ++r) w[r] = (bf16)sv[s][nf][r];
        *reinterpret_cast<bf16x4*>(myP + (s * 16 + lo) * 128 +
            (((nf * 2 + (hi >> 1)) ^ (lo & 7)) * 16) + (hi & 1) * 8) = w;
      }
    }
    // ---- P A-frags (same-wave RAW) ----
    bf16x8 pa[2][2];
    #pragma unroll
    for (int s = 0; s < 2; ++s)
      #pragma unroll
      for (int kc = 0; kc < 2; ++kc)
        pa[s][kc] = *reinterpret_cast<const bf16x8*>(myP + (s * 16 + lo) * 128 +
            (((kc * 4 + hi) ^ (lo & 7)) * 16));
    // ---- O += P V, both sets share each V fragment ----
    #pragma unroll
    for (int nf = 0; nf < 8; ++nf) {
      const int d = nf * 16 + lo;
      const int sw = (d ^ (d >> 3)) & 7;
      const bf16* vrp = Vt + d * 64;
      #pragma unroll
      for (int kc = 0; kc < 2; ++kc) {
        const bf16x8 bv = *reinterpret_cast<const bf16x8*>(vrp + (((kc * 4 + hi) ^ sw) * 8));
        acc[0][nf] = mfma16(pa[0][kc], bv, acc[0][nf]);
        acc[1][nf] = mfma16(pa[1][kc], bv, acc[1][nf]);
      }
    }
    __syncthreads();
  }

  // ---- finalize per set ----
  #pragma unroll
  for (int s = 0; s < 2; ++s) {
    const float linv = 1.f / l_run[s];
    float la[4];
    #pragma unroll
    for (int r = 0; r < 4; ++r) la[r] = __shfl(linv, hi * 4 + r, 64);
    #pragma unroll
    for (int nf = 0; nf < 8; ++nf)
      #pragma unroll
      for (int r = 0; r < 4; ++r) {
        const size_t row = q0 + wid * 32 + s * 16 + hi * 4 + r;
        Og[hoff + row * DM + nf * 16 + lo] = (bf16)(acc[s][nf][r] * la[r]);
      }
  }
}

extern "C" void kernel_launch(void* const* d_in, const int* in_sizes, int n_in,
                              void* d_out, int out_size, void* d_ws, size_t ws_size,
                              hipStream_t stream) {
  const float* x  = (const float*)d_in[0];
  const float* wq = (const float*)d_in[1];
  const float* wk = (const float*)d_in[2];
  const float* wv = (const float*)d_in[3];
  const float* wo = (const float*)d_in[4];
  const float* fc = (const float*)d_in[5];
  const float* fs = (const float*)d_in[6];
  float* out = (float*)d_out;

  char* ws = (char*)d_ws;
  bf16* xb    = (bf16*)ws;                      // 16MB  x bf16; reused as O
  bf16* wqkvt = (bf16*)(ws + (16ull << 20));    // 24MB
  bf16* wot   = (bf16*)(ws + (40ull << 20));    //  8MB
  bf16* qkv   = (bf16*)(ws + (48ull << 20));    // 48MB
  bf16* Qb = qkv;
  bf16* Kb = qkv + (size_t)MR * DM;
  bf16* Vb = qkv + 2 * (size_t)MR * DM;

  cvt_x<<<8192, 256, 0, stream>>>(x, xb);
  transpose_w<<<dim3(64, 64, 4), dim3(32, 8), 0, stream>>>(wq, wk, wv, wo, wqkvt, wot);
  gemm8<false><<<384, 512, 0, stream>>>(xb, wqkvt, (void*)qkv, MR, DM, DM);
  rope_k<<<dim3(4096, 2), 256, 0, stream>>>(Qb, Kb, fc, fs);
  flash_fwd<<<dim3(16, 16, 2), 256, 0, stream>>>(Qb, Kb, Vb, xb /*O*/);
  gemm8<true><<<128, 512, 0, stream>>>(xb, wot, (void*)out, MR, DM, DM);
}